// Round 4
// baseline (137.730 us; speedup 1.0000x reference)
//
#include <hip/hip_runtime.h>

#define TEMP 0.05f
#define EPS 1e-8f
#define NROWS 16384
#define DDIM 1024

#define ROWS_PER_WAVE 2
#define NWAVES (NROWS / ROWS_PER_WAVE)        // 8192 waves
#define NBLOCKS (NWAVES / 4)                  // 2048 blocks = 8 blocks/CU exactly

typedef float vf4 __attribute__((ext_vector_type(4)));

__global__ __launch_bounds__(256) void byol_rows_kernel(
        const float* __restrict__ a, const float* __restrict__ b,
        float* __restrict__ partials) {
    const int wave = threadIdx.x >> 6;
    const int lane = threadIdx.x & 63;
    const int wgid = blockIdx.x * 4 + wave;      // global wave id, 0..8191

    float lsum = 0.f;

#pragma unroll
    for (int r = 0; r < ROWS_PER_WAVE; ++r) {
        const size_t row = (size_t)wgid * ROWS_PER_WAVE + r;   // adjacent rows
        const vf4* a4 = (const vf4*)(a + row * DDIM);
        const vf4* b4 = (const vf4*)(b + row * DDIM);

        // 8-deep nontemporal load batch (128 B/lane in flight), then math.
        vf4 av[4], bv[4];
#pragma unroll
        for (int j = 0; j < 4; ++j)
            av[j] = __builtin_nontemporal_load(&a4[lane + 64 * j]);
#pragma unroll
        for (int j = 0; j < 4; ++j)
            bv[j] = __builtin_nontemporal_load(&b4[lane + 64 * j]);

        float dot = 0.f, aa = 0.f, bb = 0.f;
#pragma unroll
        for (int j = 0; j < 4; ++j) {
            dot += av[j].x * bv[j].x + av[j].y * bv[j].y
                 + av[j].z * bv[j].z + av[j].w * bv[j].w;
            aa  += av[j].x * av[j].x + av[j].y * av[j].y
                 + av[j].z * av[j].z + av[j].w * av[j].w;
            bb  += bv[j].x * bv[j].x + bv[j].y * bv[j].y
                 + bv[j].z * bv[j].z + bv[j].w * bv[j].w;
        }

#pragma unroll
        for (int off = 32; off > 0; off >>= 1) {
            dot += __shfl_down(dot, off, 64);
            aa  += __shfl_down(aa,  off, 64);
            bb  += __shfl_down(bb,  off, 64);
        }

        if (lane == 0) {
            float c = dot / (fmaxf(sqrtf(aa), EPS) * fmaxf(sqrtf(bb), EPS));
            lsum += 2.0f - 2.0f * c;
        }
    }

    // No LDS, no __syncthreads: one store per wave.
    if (lane == 0) partials[wgid] = lsum;
}

__global__ __launch_bounds__(256) void byol_final_kernel(
        const float* __restrict__ partials, float* __restrict__ out) {
    float sum = 0.f;
#pragma unroll
    for (int j = 0; j < NWAVES / 256; ++j)
        sum += partials[threadIdx.x + 256 * j];

#pragma unroll
    for (int off = 32; off > 0; off >>= 1)
        sum += __shfl_down(sum, off, 64);

    __shared__ float s[4];
    const int wave = threadIdx.x >> 6;
    const int lane = threadIdx.x & 63;
    if (lane == 0) s[wave] = sum;
    __syncthreads();
    if (threadIdx.x == 0) {
        out[0] = (s[0] + s[1] + s[2] + s[3]) * (1.0f / ((float)NROWS * TEMP));
    }
}

extern "C" void kernel_launch(void* const* d_in, const int* in_sizes, int n_in,
                              void* d_out, int out_size, void* d_ws, size_t ws_size,
                              hipStream_t stream) {
    const float* a = (const float*)d_in[0];
    const float* b = (const float*)d_in[1];
    float* out = (float*)d_out;
    float* partials = (float*)d_ws;   // NWAVES floats = 32 KB

    byol_rows_kernel<<<NBLOCKS, 256, 0, stream>>>(a, b, partials);
    byol_final_kernel<<<1, 256, 0, stream>>>(partials, out);
}